// Round 1
// baseline (480.543 us; speedup 1.0000x reference)
//
#include <hip/hip_runtime.h>
#include <math.h>

#define NN 50000
#define NE 640000
#define HIDC 128
#define K1 288            // 2*128+1+3 = 260 padded to multiple of 32
#define A1S 320           // LDS row stride (bf16) for A1: 640B = 5*128B (swizzle-aligned)
#define ETILES (NE/64)    // 10000 exactly
#define EBLOCKS 512
#define NTILES ((NN + 63)/64)

typedef short  short8 __attribute__((ext_vector_type(8)));
typedef __bf16 bf16x8 __attribute__((ext_vector_type(8)));
typedef float  f32x4  __attribute__((ext_vector_type(4)));

__device__ __forceinline__ unsigned short f2bf(float f) {
    unsigned int b = __float_as_uint(f);
    b += 0x7FFFu + ((b >> 16) & 1u);          // RTNE
    return (unsigned short)(b >> 16);
}
__device__ __forceinline__ float silu_f(float v) {
    return v / (1.0f + __expf(-v));
}

// ---------------- prep: f32 -> bf16 conversions ----------------
__global__ void conv_x_kernel(const float* __restrict__ x, unsigned short* __restrict__ xb) {
    const int i = blockIdx.x * 256 + threadIdx.x;
    if (i < NN * HIDC) xb[i] = f2bf(x[i]);
}

// weights transposed to [n][k] row-major bf16 so B-fragments are contiguous 16B loads
__global__ void conv_w_kernel(const float* __restrict__ Wm1, const float* __restrict__ Wm2,
                              const float* __restrict__ Wc1, const float* __restrict__ Wn1,
                              const float* __restrict__ Wn2,
                              unsigned short* __restrict__ wt1, unsigned short* __restrict__ wt2,
                              unsigned short* __restrict__ wtc1, unsigned short* __restrict__ wtn1,
                              unsigned short* __restrict__ wtn2) {
    const int i = blockIdx.x * 256 + threadIdx.x;
    const int C0 = 128 * K1;              // 36864
    if (i < C0) {
        const int n = i / K1, k = i % K1;
        wt1[i] = (k < 260) ? f2bf(Wm1[k * 128 + n]) : (unsigned short)0;
    } else if (i < C0 + 16384) {
        const int j = i - C0; const int n = j >> 7, k = j & 127;
        wt2[j] = f2bf(Wm2[k * 128 + n]);
    } else if (i < C0 + 2 * 16384) {
        const int j = i - C0 - 16384; const int n = j >> 7, k = j & 127;
        wtc1[j] = f2bf(Wc1[k * 128 + n]);
    } else if (i < C0 + 2 * 16384 + 32768) {
        const int j = i - C0 - 2 * 16384; const int n = j >> 8, k = j & 255;
        wtn1[j] = f2bf(Wn1[k * 128 + n]);
    } else if (i < C0 + 2 * 16384 + 32768 + 16384) {
        const int j = i - C0 - 2 * 16384 - 32768; const int n = j >> 7, k = j & 127;
        wtn2[j] = f2bf(Wn2[k * 128 + n]);
    }
}

// ---------------- fused edge kernel ----------------
// 512 threads = 8 waves; 64-edge tile; wave w owns output cols [16w,16w+16).
// LDS tiles XOR-swizzled on 16B granules: elem (r,k) stored at col k ^ ((r&7)<<3).
__launch_bounds__(512, 4)
__global__ void edge_kernel(
    const unsigned short* __restrict__ xb, const float* __restrict__ pos,
    const int* __restrict__ ei, const float* __restrict__ eattr,
    const unsigned short* __restrict__ wt1, const unsigned short* __restrict__ wt2,
    const unsigned short* __restrict__ wtc1,
    const float* __restrict__ bm1v, const float* __restrict__ bm2v,
    const float* __restrict__ bc1v, const float* __restrict__ wc2v,
    const float* __restrict__ bc2v,
    float* __restrict__ agg, float* __restrict__ cagg)
{
    __shared__ __align__(16) unsigned short A1[64][A1S];   // 40 KB msg_input
    __shared__ __align__(16) unsigned short H2[64][HIDC];  // 16 KB
    __shared__ __align__(16) unsigned short M3[64][HIDC];  // 16 KB msg (bf16)
    __shared__ float DIFF[64][4];                          // dx,dy,dz,dist
    __shared__ float CW[8][64];                            // coord_w partials per wave
    __shared__ int SRC[64];
    __shared__ int DST[64];

    const int tid = threadIdx.x;
    const int lane = tid & 63;
    const int wid = tid >> 6;
    const int lr = lane & 15;      // D col within tile / A row low bits
    const int lg = lane >> 4;      // k-chunk
    const int mycol = wid * 16 + lr;

    const float bm1_l = bm1v[mycol];
    const float bm2_l = bm2v[mycol];
    const float bc1_l = bc1v[mycol];
    const float wc2_l = wc2v[mycol];
    const float bc2_s = bc2v[0];

    const int bi = tid >> 3;       // edge-in-tile for build phase
    const int bj = tid & 7;
    const f32x4 z4 = {0.f, 0.f, 0.f, 0.f};

    for (int tile = blockIdx.x; tile < ETILES; tile += gridDim.x) {
        const int e0 = tile * 64;
        __syncthreads();                       // protect LDS vs previous iter readers
        if (tid < 64) {
            const int e = e0 + tid;
            const int s = ei[e];
            const int d = ei[NE + e];
            SRC[tid] = s; DST[tid] = d;
            const float dx = pos[s*3+0] - pos[d*3+0];
            const float dy = pos[s*3+1] - pos[d*3+1];
            const float dz = pos[s*3+2] - pos[d*3+2];
            DIFF[tid][0] = dx; DIFF[tid][1] = dy; DIFF[tid][2] = dz;
            DIFF[tid][3] = sqrtf(dx*dx + dy*dy + dz*dz);
        }
        __syncthreads();

        { // build A1 = [x[src] | x[dst] | dist | edge_attr | 0-pad], bf16, swizzled
            const int s = SRC[bi], d = DST[bi];
            #pragma unroll
            for (int gi = 0; gi < 5; ++gi) {
                const int g = bj + gi * 8;     // logical granule 0..39
                unsigned short* dp = &A1[bi][0] + (((g ^ (bi & 7))) << 3);
                if (g < 16) {
                    *reinterpret_cast<short8*>(dp) =
                        *reinterpret_cast<const short8*>(xb + (size_t)s * HIDC + (g << 3));
                } else if (g < 32) {
                    *reinterpret_cast<short8*>(dp) =
                        *reinterpret_cast<const short8*>(xb + (size_t)d * HIDC + ((g - 16) << 3));
                } else if (g == 32) {
                    const int e = e0 + bi;
                    short8 v = {0,0,0,0,0,0,0,0};
                    v[0] = (short)f2bf(DIFF[bi][3]);
                    v[1] = (short)f2bf(eattr[e*3+0]);
                    v[2] = (short)f2bf(eattr[e*3+1]);
                    v[3] = (short)f2bf(eattr[e*3+2]);
                    *reinterpret_cast<short8*>(dp) = v;
                } else {
                    short8 v = {0,0,0,0,0,0,0,0};
                    *reinterpret_cast<short8*>(dp) = v;
                }
            }
        }
        __syncthreads();

        // GEMM1: [64,288] @ Wm1 -> h, SiLU
        f32x4 acc[4] = {z4, z4, z4, z4};
        #pragma unroll
        for (int kk = 0; kk < 9; ++kk) {
            const bf16x8 b = *reinterpret_cast<const bf16x8*>(wt1 + (size_t)mycol * K1 + kk * 32 + lg * 8);
            #pragma unroll
            for (int m = 0; m < 4; ++m) {
                const int r = m * 16 + lr;
                const int g = (kk * 4 + lg) ^ (r & 7);
                const bf16x8 a = *reinterpret_cast<const bf16x8*>(&A1[r][0] + (g << 3));
                acc[m] = __builtin_amdgcn_mfma_f32_16x16x32_bf16(a, b, acc[m], 0, 0, 0);
            }
        }
        #pragma unroll
        for (int m = 0; m < 4; ++m) {
            #pragma unroll
            for (int q = 0; q < 4; ++q) {
                const int r = m * 16 + lg * 4 + q;            // verified C/D: row=(l>>4)*4+q
                H2[r][mycol ^ ((r & 7) << 3)] = f2bf(silu_f(acc[m][q] + bm1_l));
            }
        }
        __syncthreads();

        // GEMM2: h @ Wm2 -> msg, SiLU; atomics to agg from f32 regs
        f32x4 acc2[4] = {z4, z4, z4, z4};
        #pragma unroll
        for (int kk = 0; kk < 4; ++kk) {
            const bf16x8 b = *reinterpret_cast<const bf16x8*>(wt2 + (size_t)mycol * HIDC + kk * 32 + lg * 8);
            #pragma unroll
            for (int m = 0; m < 4; ++m) {
                const int r = m * 16 + lr;
                const int g = (kk * 4 + lg) ^ (r & 7);
                const bf16x8 a = *reinterpret_cast<const bf16x8*>(&H2[r][0] + (g << 3));
                acc2[m] = __builtin_amdgcn_mfma_f32_16x16x32_bf16(a, b, acc2[m], 0, 0, 0);
            }
        }
        #pragma unroll
        for (int m = 0; m < 4; ++m) {
            #pragma unroll
            for (int q = 0; q < 4; ++q) {
                const int r = m * 16 + lg * 4 + q;
                const float mv = silu_f(acc2[m][q] + bm2_l);
                M3[r][mycol ^ ((r & 7) << 3)] = f2bf(mv);
                atomicAdd(&agg[(size_t)SRC[r] * HIDC + mycol], mv);
            }
        }
        __syncthreads();

        // GEMM3: msg @ Wc1 -> t, SiLU; coord_w = t . Wc2 (+bc2)
        f32x4 acc3[4] = {z4, z4, z4, z4};
        #pragma unroll
        for (int kk = 0; kk < 4; ++kk) {
            const bf16x8 b = *reinterpret_cast<const bf16x8*>(wtc1 + (size_t)mycol * HIDC + kk * 32 + lg * 8);
            #pragma unroll
            for (int m = 0; m < 4; ++m) {
                const int r = m * 16 + lr;
                const int g = (kk * 4 + lg) ^ (r & 7);
                const bf16x8 a = *reinterpret_cast<const bf16x8*>(&M3[r][0] + (g << 3));
                acc3[m] = __builtin_amdgcn_mfma_f32_16x16x32_bf16(a, b, acc3[m], 0, 0, 0);
            }
        }
        #pragma unroll
        for (int m = 0; m < 4; ++m) {
            #pragma unroll
            for (int q = 0; q < 4; ++q) {
                float tv = silu_f(acc3[m][q] + bc1_l) * wc2_l;
                tv += __shfl_xor(tv, 1, 64);
                tv += __shfl_xor(tv, 2, 64);
                tv += __shfl_xor(tv, 4, 64);
                tv += __shfl_xor(tv, 8, 64);
                if (lr == 0) CW[wid][m * 16 + lg * 4 + q] = tv;
            }
        }
        __syncthreads();

        if (tid < 64) {
            float s = bc2_s;
            #pragma unroll
            for (int w = 0; w < 8; ++w) s += CW[w][tid];
            const int sn = SRC[tid];
            atomicAdd(&cagg[sn * 3 + 0], DIFF[tid][0] * s);
            atomicAdd(&cagg[sn * 3 + 1], DIFF[tid][1] * s);
            atomicAdd(&cagg[sn * 3 + 2], DIFF[tid][2] * s);
        }
    }
}

// ---------------- node kernel: x_new + pos_new ----------------
__launch_bounds__(512, 4)
__global__ void node_kernel(
    const unsigned short* __restrict__ xb, const float* __restrict__ agg,
    const unsigned short* __restrict__ wtn1, const unsigned short* __restrict__ wtn2,
    const float* __restrict__ bn1v, const float* __restrict__ bn2v,
    const float* __restrict__ pos, const float* __restrict__ cagg,
    float* __restrict__ outx, float* __restrict__ outp)
{
    __shared__ __align__(16) unsigned short AN[64][256];   // [x | agg] bf16, swizzled
    __shared__ __align__(16) unsigned short HN[64][HIDC];
    const int tid = threadIdx.x;
    const int lane = tid & 63;
    const int wid = tid >> 6;
    const int lr = lane & 15;
    const int lg = lane >> 4;
    const int mycol = wid * 16 + lr;
    const float bn1_l = bn1v[mycol];
    const float bn2_l = bn2v[mycol];
    const f32x4 z4 = {0.f, 0.f, 0.f, 0.f};
    const int n0 = blockIdx.x * 64;

    {
        const int i = tid >> 3, j = tid & 7;
        const int n = n0 + i;
        const bool ok = (n < NN);
        #pragma unroll
        for (int gi = 0; gi < 4; ++gi) {
            const int g = j + gi * 8;          // 0..31
            unsigned short* dp = &AN[i][0] + (((g ^ (i & 7))) << 3);
            short8 v = {0,0,0,0,0,0,0,0};
            if (ok) {
                if (g < 16) {
                    v = *reinterpret_cast<const short8*>(xb + (size_t)n * HIDC + (g << 3));
                } else {
                    const float* ap = agg + (size_t)n * HIDC + ((g - 16) << 3);
                    #pragma unroll
                    for (int c = 0; c < 8; ++c) v[c] = (short)f2bf(ap[c]);
                }
            }
            *reinterpret_cast<short8*>(dp) = v;
        }
    }
    __syncthreads();

    f32x4 acc[4] = {z4, z4, z4, z4};
    #pragma unroll
    for (int kk = 0; kk < 8; ++kk) {
        const bf16x8 b = *reinterpret_cast<const bf16x8*>(wtn1 + (size_t)mycol * 256 + kk * 32 + lg * 8);
        #pragma unroll
        for (int m = 0; m < 4; ++m) {
            const int r = m * 16 + lr;
            const int g = (kk * 4 + lg) ^ (r & 7);
            const bf16x8 a = *reinterpret_cast<const bf16x8*>(&AN[r][0] + (g << 3));
            acc[m] = __builtin_amdgcn_mfma_f32_16x16x32_bf16(a, b, acc[m], 0, 0, 0);
        }
    }
    #pragma unroll
    for (int m = 0; m < 4; ++m) {
        #pragma unroll
        for (int q = 0; q < 4; ++q) {
            const int r = m * 16 + lg * 4 + q;
            HN[r][mycol ^ ((r & 7) << 3)] = f2bf(silu_f(acc[m][q] + bn1_l));
        }
    }
    __syncthreads();

    f32x4 acc2[4] = {z4, z4, z4, z4};
    #pragma unroll
    for (int kk = 0; kk < 4; ++kk) {
        const bf16x8 b = *reinterpret_cast<const bf16x8*>(wtn2 + (size_t)mycol * HIDC + kk * 32 + lg * 8);
        #pragma unroll
        for (int m = 0; m < 4; ++m) {
            const int r = m * 16 + lr;
            const int g = (kk * 4 + lg) ^ (r & 7);
            const bf16x8 a = *reinterpret_cast<const bf16x8*>(&HN[r][0] + (g << 3));
            acc2[m] = __builtin_amdgcn_mfma_f32_16x16x32_bf16(a, b, acc2[m], 0, 0, 0);
        }
    }
    #pragma unroll
    for (int m = 0; m < 4; ++m) {
        #pragma unroll
        for (int q = 0; q < 4; ++q) {
            const int n = n0 + m * 16 + lg * 4 + q;
            if (n < NN) outx[(size_t)n * HIDC + mycol] = acc2[m][q] + bn2_l;
        }
    }
    if (tid < 192) {
        const int r = n0 + tid / 3;
        const int d2 = tid - (tid / 3) * 3;
        if (r < NN) outp[r * 3 + d2] = pos[r * 3 + d2] + cagg[r * 3 + d2];
    }
}

// ---------------- launch ----------------
extern "C" void kernel_launch(void* const* d_in, const int* in_sizes, int n_in,
                              void* d_out, int out_size, void* d_ws, size_t ws_size,
                              hipStream_t stream)
{
    const float* x   = (const float*)d_in[0];
    const float* pos = (const float*)d_in[1];
    const int*   ei  = (const int*)d_in[2];
    const float* ea  = (const float*)d_in[3];
    const float* Wm1 = (const float*)d_in[4];
    const float* bm1 = (const float*)d_in[5];
    const float* Wm2 = (const float*)d_in[6];
    const float* bm2 = (const float*)d_in[7];
    const float* Wn1 = (const float*)d_in[8];
    const float* bn1 = (const float*)d_in[9];
    const float* Wn2 = (const float*)d_in[10];
    const float* bn2 = (const float*)d_in[11];
    const float* Wc1 = (const float*)d_in[12];
    const float* bc1 = (const float*)d_in[13];
    const float* Wc2 = (const float*)d_in[14];
    const float* bc2 = (const float*)d_in[15];

    // workspace layout (bytes), all 64B-aligned; total ~39.3 MB
    char* ws = (char*)d_ws;
    unsigned short* xb   = (unsigned short*)(ws);              // 12,800,000
    float* agg           = (float*)(ws + 12800000);            // 25,600,000
    float* cagg          = (float*)(ws + 38400000);            //    600,000
    unsigned short* wt1  = (unsigned short*)(ws + 39000000);   //     73,728
    unsigned short* wt2  = (unsigned short*)(ws + 39073728);   //     32,768
    unsigned short* wtc1 = (unsigned short*)(ws + 39106496);   //     32,768
    unsigned short* wtn1 = (unsigned short*)(ws + 39139264);   //     65,536
    unsigned short* wtn2 = (unsigned short*)(ws + 39204800);   //     32,768

    float* outx = (float*)d_out;
    float* outp = outx + (size_t)NN * HIDC;

    hipMemsetAsync(agg, 0, (size_t)NN * HIDC * sizeof(float), stream);
    hipMemsetAsync(cagg, 0, (size_t)NN * 3 * sizeof(float), stream);
    conv_x_kernel<<<(NN * HIDC + 255) / 256, 256, 0, stream>>>(x, xb);
    conv_w_kernel<<<(118784 + 255) / 256, 256, 0, stream>>>(Wm1, Wm2, Wc1, Wn1, Wn2,
                                                            wt1, wt2, wtc1, wtn1, wtn2);
    edge_kernel<<<EBLOCKS, 512, 0, stream>>>(xb, pos, ei, ea, wt1, wt2, wtc1,
                                             bm1, bm2, bc1, Wc2, bc2, agg, cagg);
    node_kernel<<<NTILES, 512, 0, stream>>>(xb, agg, wtn1, wtn2, bn1, bn2, pos, cagg, outx, outp);
}